// Round 5
// baseline (7754.040 us; speedup 1.0000x reference)
//
#include <hip/hip_runtime.h>
#include <math.h>

#define NUM_PB 32
#define PBDIM  16
#define DDIM   64
#define HDIM   1024
#define BDIM   64

typedef __attribute__((ext_vector_type(8))) short bf16x8;
typedef __attribute__((ext_vector_type(4))) float f32x4;
typedef __attribute__((ext_vector_type(4))) unsigned int u32x4;

// LDS: 4 weight matrices [16][WST] bf16 + tmpf [16][64] fp32 + sH [64][4] ushort
#define WST    1032                      // 1024 + 8 pad (2064 B)
#define SW_MAT (16 * WST)
#define SMEM_BYTES (4 * SW_MAT * 2 + 16 * 64 * 4 + 512)   // 132096 + 4096 + 512 = 136704 B

#define CTR_BASE 0xAAAAAAAAu             // harness poisons ws with 0xAA every launch

struct Params {
    const int*   label;
    const int*   fcl;
    const float* mu_pb;
    const float* logvar_pb;
    const float* Wi0;
    const float* Wh0;
    const float* bi0;
    const float* bh0;
    const float* Wi1;
    const float* Wh1;
    const float* bi1;
    const float* bh1;
    const float* Wlin;
    const float* blin;
    float*       out;
    float*       ws;
};

__device__ __forceinline__ unsigned short f2bf(float x) {
    unsigned int u = __builtin_bit_cast(unsigned int, x);
    u += 0x7fffu + ((u >> 16) & 1u);     // RNE
    return (unsigned short)(u >> 16);
}
__device__ __forceinline__ float sigf(float x)  { return 1.0f / (1.0f + __expf(-x)); }
__device__ __forceinline__ float tanh_(float x) { float e = __expf(2.0f * x); return 1.0f - 2.0f / (e + 1.0f); }

// MFMA with A streamed (LDS or global, cached) and B from register fragments.
template <int K0, int K1>
__device__ __forceinline__ void mfma_regB(const unsigned short* __restrict__ Ab,
                                          const bf16x8* Bf, f32x4* accs) {
#pragma unroll
    for (int kb = K0; kb < K1; ++kb) {
        bf16x8 a = *(const bf16x8*)(Ab + kb * 32);
        accs[kb & 3] = __builtin_amdgcn_mfma_f32_16x16x32_bf16(a, Bf[kb], accs[kb & 3], 0, 0, 0);
    }
}

// Issue 32 NORMAL CACHED loads (L1+L2). Freshness is guaranteed by the
// per-wave acquire fence (buffer_inv) executed in gbar_wait_fast before
// these are issued: h lines are never dirty in L2 (publishes are
// write-through agent atomics), so the 32 blocks of an XCD share one
// L3->L2 fill per window instead of 32 bypass reads. Caller does the
// counted s_waitcnt + sched_barrier (rule #18) before consuming dst.
__device__ __forceinline__ void issue_frag_loads(const unsigned short* __restrict__ g, bf16x8* dst) {
#pragma unroll
    for (int kb = 0; kb < 32; ++kb)
        asm volatile("global_load_dwordx4 %0, %1, off"
                     : "=v"(dst[kb]) : "v"(g + kb * 32));
}
#define VMWAIT(N) do { asm volatile("s_waitcnt vmcnt(" #N ")" ::: "memory"); \
                       __builtin_amdgcn_sched_barrier(0); } while (0)

// ---- FLAT SEQ-VECTOR BARRIER ----
// seq[bid] (256 dwords, ws bytes [0,1024), poison-based 0xAAAAAAAA+barIdx).
// Each block writes ONLY its own word (no RMW, no contention). A poller wave
// reads the whole array with one dwordx4 per lane (64 lanes x 16 B = 1 KB)
// and __all-reduces. Ordering: producer's s_waitcnt vmcnt(0) sits between
// its h-stores and its seq store, so "all 256 seqs >= target" at L3 implies
// all h data is at L3; consumers then ACQUIRE (per-wave buffer_inv) and
// read h through the now-clean L1/L2 (miss -> fresh L3 fill, XCD-shared).

// wait: wave 0 gather-polls (bypass loads); syncthreads releases the block;
// then EVERY wave executes an agent-acquire fence (s_waitcnt + buffer_inv).
// Per-wave fence is the memory-model-sanctioned form: it orders THAT wave's
// subsequent vmem loads after the L1/L2 invalidate. h lines are never dirty
// (write-through publishes) so inv loses nothing; dirty out/wlg lines
// survive inv (acquire fences must not corrupt pending stores).
__device__ __forceinline__ void gbar_wait_fast(char* wsBase, int tid, unsigned barIdx) {
    if (tid < 64) {
        const u32x4* sp = (const u32x4*)wsBase + tid;   // lane i -> seq[4i..4i+3]
        unsigned tgt = CTR_BASE + barIdx;
        while (true) {
            u32x4 v;
            asm volatile("global_load_dwordx4 %0, %1, off sc0 sc1\n\t"
                         "s_waitcnt vmcnt(0)"
                         : "=v"(v) : "v"(sp) : "memory");
            int ok = (v.x >= tgt) && (v.y >= tgt) && (v.z >= tgt) && (v.w >= tgt);
            if (__all(ok)) break;
            __builtin_amdgcn_s_sleep(1);
        }
    }
    __syncthreads();
    __builtin_amdgcn_fence(__ATOMIC_ACQUIRE, "agent");   // inv stale L1/L2 h lines
}

// arrive: syncthreads -> wave0 publishes this block's h rows as 64x 8B
// agent-scope atomic stores (write through to the L3 coherence point) ->
// s_waitcnt vmcnt(0) -> store own seq word. NO release fence, NO RMW.
// Waves 1..3 fall through immediately into the hidden (reg/LDS) work.
__device__ __forceinline__ void gbar_arrive_fast(char* wsBase, unsigned short* dst,
                                                 const unsigned short* sH,
                                                 int bid, int tid, unsigned barIdx) {
    __syncthreads();                      // sH writes visible block-wide
    if (tid < 64) {                       // wave 0 only: 64 rows x 8 B
        unsigned long long v = *(const unsigned long long*)(sH + tid * 4);
        __hip_atomic_store((unsigned long long*)(dst + (size_t)tid * 1024), v,
                           __ATOMIC_RELAXED, __HIP_MEMORY_SCOPE_AGENT);
    }
    if (tid == 0) {
        asm volatile("s_waitcnt vmcnt(0)" ::: "memory");   // h stores at L3 before seq
        __hip_atomic_store((unsigned*)(wsBase + (size_t)bid * 4), CTR_BASE + barIdx,
                           __ATOMIC_RELAXED, __HIP_MEMORY_SCOPE_AGENT);
    }
}

// ---- init-only full barrier (fenced; publishes normal cached init stores) ----
__device__ __forceinline__ void gbar_full(char* wsBase, int bid, int tid, unsigned barIdx) {
    __syncthreads();
    if (tid == 0) {
        __builtin_amdgcn_fence(__ATOMIC_RELEASE, "agent");   // wbl2: flush init stores
        __hip_atomic_store((unsigned*)(wsBase + (size_t)bid * 4), CTR_BASE + barIdx,
                           __ATOMIC_RELAXED, __HIP_MEMORY_SCOPE_AGENT);
    }
    if (tid < 64) {
        const u32x4* sp = (const u32x4*)wsBase + tid;
        unsigned tgt = CTR_BASE + barIdx;
        while (true) {
            u32x4 v;
            asm volatile("global_load_dwordx4 %0, %1, off sc0 sc1\n\t"
                         "s_waitcnt vmcnt(0)"
                         : "=v"(v) : "v"(sp) : "memory");
            int ok = (v.x >= tgt) && (v.y >= tgt) && (v.z >= tgt) && (v.w >= tgt);
            if (__all(ok)) break;
            __builtin_amdgcn_s_sleep(1);
        }
    }
    __syncthreads();
    __builtin_amdgcn_fence(__ATOMIC_ACQUIRE, "agent");       // inv stale L1/L2 copies
}

// 256 blocks x 256 threads, 1 block/CU. Block owns j0=bid*4; gate-rows m=jq*4+gate.
// Wf recurrence (gates0 = Wf*h1(t-1) + Wh0*h0(t-1) + const, Wf = Wi0_y @ Wlin).
// Steady state: h published via write-through agent atomics; consumers
// acquire (per-wave inv) then read h through L1/L2 so each XCD's 32 blocks
// share one L3 fill per window. Sync via the flat seq barrier.
__global__ void __launch_bounds__(256, 1) rnn_kernel(Params p) {
    extern __shared__ __align__(16) unsigned short smem[];
    unsigned short* sWf  = smem;
    unsigned short* sWh0 = sWf + SW_MAT;
    unsigned short* sWi1 = sWh0 + SW_MAT;
    unsigned short* sWh1 = sWi1 + SW_MAT;
    float* tmpf = (float*)(smem + 4 * SW_MAT);    // [16][64] Wi0 y-columns fp32
    unsigned short* sH = (unsigned short*)(tmpf + 16 * 64);   // [64][4] h staging

    const int tid = threadIdx.x, bid = blockIdx.x;
    const int lane = tid & 63, w = tid >> 6;
    const int lm = lane & 15, lq = lane >> 4;
    const int bcol0 = w * 16;
    const int bb = bcol0 + lm;
    const int j0 = bid * 4, jj = j0 + lq;
    const int T = p.fcl[0];

    // ws (ushort): seq region [64][128] (seq[256] dwords in bytes [0,1024),
    // POISON-BASED; rest of the 16 KB unused) | h0[2][64][1024] | h1[2][64][1024]
    // | wlin_bf[64][1024]
    unsigned short* x80g = (unsigned short*)p.ws;
    unsigned short* h0g  = x80g + 64 * 128;
    unsigned short* h1g  = h0g + 2 * 65536;
    unsigned short* wlg  = h1g + 2 * 65536;

    // ---------------- init ----------------
    for (int idx = tid; idx < 16 * 1024; idx += 256) {    // recurrent weights -> LDS bf16
        int m = idx >> 10, k = idx & 1023;
        int gi = m & 3, jq = m >> 2;
        size_t row = (size_t)(gi * HDIM + j0 + jq);
        sWh0[m * WST + k] = f2bf(p.Wh0[row * HDIM + k]);
        sWi1[m * WST + k] = f2bf(p.Wi1[row * HDIM + k]);
        sWh1[m * WST + k] = f2bf(p.Wh1[row * HDIM + k]);
    }
    for (int i = tid; i < 16 * 64; i += 256) {            // Wi0 y-columns -> LDS fp32
        int m = i >> 6, d = i & 63;
        int gi = m & 3, jq = m >> 2;
        tmpf[i] = p.Wi0[(size_t)(gi * HDIM + j0 + jq) * (DDIM + PBDIM) + d];
    }
    __syncthreads();
    {   // Wf = Wi0_y @ Wlin -> LDS bf16. thread: row m=tid>>4, k-chunk c=tid&15.
        int m = tid >> 4, c = tid & 15;
        const float* wrow = tmpf + m * 64;
        for (int pass = 0; pass < 4; ++pass) {
            int k0 = c * 64 + pass * 16;
            float acc[16];
#pragma unroll
            for (int i = 0; i < 16; ++i) acc[i] = 0.f;
            for (int d = 0; d < 64; ++d) {
                float wv = wrow[d];
                const float4* wl = (const float4*)(p.Wlin + (size_t)d * HDIM + k0);
                float4 a0 = wl[0], a1 = wl[1], a2 = wl[2], a3 = wl[3];
                acc[0]  = fmaf(wv, a0.x, acc[0]);  acc[1]  = fmaf(wv, a0.y, acc[1]);
                acc[2]  = fmaf(wv, a0.z, acc[2]);  acc[3]  = fmaf(wv, a0.w, acc[3]);
                acc[4]  = fmaf(wv, a1.x, acc[4]);  acc[5]  = fmaf(wv, a1.y, acc[5]);
                acc[6]  = fmaf(wv, a1.z, acc[6]);  acc[7]  = fmaf(wv, a1.w, acc[7]);
                acc[8]  = fmaf(wv, a2.x, acc[8]);  acc[9]  = fmaf(wv, a2.y, acc[9]);
                acc[10] = fmaf(wv, a2.z, acc[10]); acc[11] = fmaf(wv, a2.w, acc[11]);
                acc[12] = fmaf(wv, a3.x, acc[12]); acc[13] = fmaf(wv, a3.y, acc[13]);
                acc[14] = fmaf(wv, a3.z, acc[14]); acc[15] = fmaf(wv, a3.w, acc[15]);
            }
#pragma unroll
            for (int i = 0; i < 16; ++i) sWf[m * WST + k0 + i] = f2bf(acc[i]);
        }
    }
    // per-lane constants. accT0 = biases + Wi0_pb*pb(b) (t=0 uses y_prev=0!);
    // yb = Wi0_y*blin, added only for t>=1 when y(t-1)=Wlin*h1+blin is live.
    float accT0[4], yb[4], bias1[4];
    {
        int lbl = p.label[bb];
#pragma unroll
        for (int r = 0; r < 4; ++r) {
            float a0_ = p.bi0[r * HDIM + jj] + p.bh0[r * HDIM + jj];
            const float* wpb = p.Wi0 + (size_t)(r * HDIM + jj) * (DDIM + PBDIM) + DDIM;
            const float* mu  = p.mu_pb + lbl * PBDIM;
            for (int q = 0; q < PBDIM; ++q) a0_ = fmaf(wpb[q], mu[q], a0_);
            accT0[r] = a0_;
            float y_ = 0.f;
            const float* wrow = tmpf + (lq * 4 + r) * 64;
            for (int d = 0; d < 64; ++d) y_ = fmaf(wrow[d], p.blin[d], y_);
            yb[r] = y_;
            bias1[r] = p.bi1[r * HDIM + jj] + p.bh1[r * HDIM + jj];
        }
    }
    int gid = bid * 256 + tid;            // 0..65535
    h0g[gid] = 0;                         // zero-init h state (flushed by init fence)
    h1g[gid] = 0;
    // NOTE: the legacy x80 data region is DEAD (mu folded into accT0, x implicit
    // in Wf) — no init writes there; bytes [0,1024) stay pristine poison for seq.
    if (bid < 16) {                       // Wlin -> bf16, row-major [64][1024]
        for (int i = 0; i < 16; ++i) {
            int e = bid * 4096 + i * 256 + tid;
            wlg[e] = f2bf(p.Wlin[e]);
        }
    }
    if (bid == 16 && tid < BDIM) {        // aux outputs
        int lbl = p.label[tid];
        float* out_lbl = p.out + (size_t)T * BDIM * DDIM;
        float* out_pb  = out_lbl + BDIM;
        float* out_mu  = out_pb + BDIM * PBDIM;
        float* out_lv  = out_mu + BDIM * PBDIM;
        out_lbl[tid] = (float)lbl;
        for (int q = 0; q < PBDIM; ++q) {
            float mu = p.mu_pb[lbl * PBDIM + q];
            float lv = p.logvar_pb[lbl * PBDIM + q];
            out_pb[tid * PBDIM + q] = mu;
            out_mu[tid * PBDIM + q] = mu;
            out_lv[tid * PBDIM + q] = lv;
        }
    }
    float blin4[4] = {0.f, 0.f, 0.f, 0.f};
    if (bid < 4) {
        int d0 = bid * 16 + lq * 4;
#pragma unroll
        for (int r = 0; r < 4; ++r) blin4[r] = p.blin[d0 + r];
    }
    float c0 = 0.f, c1 = 0.f;
    char* wsBase = (char*)p.ws;

    const f32x4 zf = {0.f, 0.f, 0.f, 0.f};
    unsigned barIdx = 1;
    gbar_full(wsBase, bid, tid, barIdx);  // fenced: publishes all init state to L3

    f32x4 saved0 = zf;                    // Wh0*h0(t-1): zero for t=0 (h0(-1)=0)
    f32x4 saved1 = zf;                    // Wh1*h1(t-1): recomputed each window A
    int cur = 0;
    for (int t = 0; t < T; ++t) {
        // ---- window A: h0(t) = f(Wf*h1(t-1) + saved Wh0-part + const) ----
        {
            gbar_wait_fast(wsBase, tid, barIdx);          // h1(t-1) fresh past inv
            const unsigned short* src = h1g + (size_t)cur * 65536 + (size_t)bb * 1024 + 8 * lq;
            bf16x8 bfrag[32];
            issue_frag_loads(src, bfrag);
            f32x4 accs[4] = {zf, zf, zf, zf};
            const unsigned short* Ab = sWf + lm * WST + 8 * lq;
            VMWAIT(16);
            mfma_regB<0, 16>(Ab, bfrag, accs);
            VMWAIT(0);
            mfma_regB<16, 32>(Ab, bfrag, accs);
            f32x4 s = accs[0] + accs[1] + accs[2] + accs[3];
            s += saved0;
            float addy = (t > 0) ? 1.f : 0.f;
            float gi_ = s[0] + accT0[0] + addy * yb[0];
            float gf_ = s[1] + accT0[1] + addy * yb[1];
            float gg_ = s[2] + accT0[2] + addy * yb[2];
            float go_ = s[3] + accT0[3] + addy * yb[3];
            c0 = sigf(gf_) * c0 + sigf(gi_) * tanh_(gg_);
            float h = sigf(go_) * tanh_(c0);
            sH[bb * 4 + lq] = f2bf(h);
            gbar_arrive_fast(wsBase, h0g + (size_t)(cur ^ 1) * 65536 + j0, sH, bid, tid, ++barIdx);
            // ---- hidden in barrier: y(t-1) + Wh1*h1(t-1) from reg fragments ----
            if (bid < 4 && t > 0) {                   // y(t-1) = Wlin*h1(t-1) + blin
                f32x4 ya[4] = {zf, zf, zf, zf};
                mfma_regB<0, 32>(wlg + (size_t)(bid * 16 + lm) * 1024 + 8 * lq, bfrag, ya);
                f32x4 sy = ya[0] + ya[1] + ya[2] + ya[3];
                int d0 = bid * 16 + lq * 4;
                float4 y4;
                y4.x = sy[0] + blin4[0]; y4.y = sy[1] + blin4[1];
                y4.z = sy[2] + blin4[2]; y4.w = sy[3] + blin4[3];
                *(float4*)(p.out + (size_t)(t - 1) * BDIM * DDIM + bb * DDIM + d0) = y4;
            }
            {
                f32x4 pa[4] = {zf, zf, zf, zf};
                mfma_regB<0, 32>(sWh1 + lm * WST + 8 * lq, bfrag, pa);
                saved1 = pa[0] + pa[1] + pa[2] + pa[3];
            }
        }
        // ---- window B: h1(t) = f(Wi1*h0(t) + saved Wh1-part + bias) ----
        {
            gbar_wait_fast(wsBase, tid, barIdx);          // h0(t) fresh past inv
            const unsigned short* src = h0g + (size_t)(cur ^ 1) * 65536 + (size_t)bb * 1024 + 8 * lq;
            bf16x8 bfrag[32];
            issue_frag_loads(src, bfrag);
            f32x4 accs[4] = {zf, zf, zf, zf};
            const unsigned short* Ab = sWi1 + lm * WST + 8 * lq;
            VMWAIT(16);
            mfma_regB<0, 16>(Ab, bfrag, accs);
            VMWAIT(0);
            mfma_regB<16, 32>(Ab, bfrag, accs);
            f32x4 s = accs[0] + accs[1] + accs[2] + accs[3];
            s += saved1;
            float gi_ = s[0] + bias1[0], gf_ = s[1] + bias1[1];
            float gg_ = s[2] + bias1[2], go_ = s[3] + bias1[3];
            c1 = sigf(gf_) * c1 + sigf(gi_) * tanh_(gg_);
            float h = sigf(go_) * tanh_(c1);
            sH[bb * 4 + lq] = f2bf(h);
            gbar_arrive_fast(wsBase, h1g + (size_t)(cur ^ 1) * 65536 + j0, sH, bid, tid, ++barIdx);
            // ---- hidden in barrier: Wh0*h0(t) for next window A ----
            {
                f32x4 pa[4] = {zf, zf, zf, zf};
                mfma_regB<0, 32>(sWh0 + lm * WST + 8 * lq, bfrag, pa);
                saved0 = pa[0] + pa[1] + pa[2] + pa[3];
            }
        }
        cur ^= 1;
    }
    // ---- tail: y(T-1) (h1(T-1) is in h1g[cur] after the final flip) ----
    gbar_wait_fast(wsBase, tid, barIdx);
    if (bid < 4 && T > 0) {
        bf16x8 bfrag[32];
        issue_frag_loads(h1g + (size_t)cur * 65536 + (size_t)bb * 1024 + 8 * lq, bfrag);
        VMWAIT(0);
        f32x4 ya[4] = {zf, zf, zf, zf};
        mfma_regB<0, 32>(wlg + (size_t)(bid * 16 + lm) * 1024 + 8 * lq, bfrag, ya);
        f32x4 sy = ya[0] + ya[1] + ya[2] + ya[3];
        int d0 = bid * 16 + lq * 4;
        float4 y4;
        y4.x = sy[0] + blin4[0]; y4.y = sy[1] + blin4[1];
        y4.z = sy[2] + blin4[2]; y4.w = sy[3] + blin4[3];
        *(float4*)(p.out + (size_t)(T - 1) * BDIM * DDIM + bb * DDIM + d0) = y4;
    }
}

extern "C" void kernel_launch(void* const* d_in, const int* in_sizes, int n_in,
                              void* d_out, int out_size, void* d_ws, size_t ws_size,
                              hipStream_t stream) {
    Params p;
    p.label     = (const int*)d_in[0];
    p.fcl       = (const int*)d_in[1];
    p.mu_pb     = (const float*)d_in[2];
    p.logvar_pb = (const float*)d_in[3];
    p.Wi0       = (const float*)d_in[4];
    p.Wh0       = (const float*)d_in[5];
    p.bi0       = (const float*)d_in[6];
    p.bh0       = (const float*)d_in[7];
    p.Wi1       = (const float*)d_in[8];
    p.Wh1       = (const float*)d_in[9];
    p.bi1       = (const float*)d_in[10];
    p.bh1       = (const float*)d_in[11];
    p.Wlin      = (const float*)d_in[12];
    p.blin      = (const float*)d_in[13];
    p.out       = (float*)d_out;
    p.ws        = (float*)d_ws;

    (void)hipFuncSetAttribute((const void*)rnn_kernel,
                              hipFuncAttributeMaxDynamicSharedMemorySize, SMEM_BYTES);
    void* args[] = { &p };
    // Kernel uses only its own ws-based barriers (no cg::grid.sync); coop launch
    // preferred for guaranteed co-residency, fallback to normal launch.
    hipError_t e = hipLaunchCooperativeKernel((void*)rnn_kernel, dim3(256), dim3(256),
                                              args, SMEM_BYTES, stream);
    if (e != hipSuccess) {
        rnn_kernel<<<dim3(256), dim3(256), SMEM_BYTES, stream>>>(p);
    }
}

// Round 7
// 2909.014 us; speedup vs baseline: 2.6655x; 2.6655x over previous
//
#include <hip/hip_runtime.h>
#include <math.h>

#define NUM_PB 32
#define PBDIM  16
#define DDIM   64
#define HDIM   1024
#define BDIM   64

typedef __attribute__((ext_vector_type(8))) short bf16x8;
typedef __attribute__((ext_vector_type(4))) float f32x4;
typedef __attribute__((ext_vector_type(4))) unsigned int u32x4;

// LDS: 4 weight matrices [16][WST] bf16 + tmpf [16][64] fp32 + sH [64][4] ushort
#define WST    1032                      // 1024 + 8 pad (2064 B)
#define SW_MAT (16 * WST)
#define SMEM_BYTES (4 * SW_MAT * 2 + 16 * 64 * 4 + 512)   // 136704 B

#define CTR_BASE 0xAAAAAAAAu             // harness poisons ws with 0xAA every launch

struct Params {
    const int*   label;
    const int*   fcl;
    const float* mu_pb;
    const float* logvar_pb;
    const float* Wi0;
    const float* Wh0;
    const float* bi0;
    const float* bh0;
    const float* Wi1;
    const float* Wh1;
    const float* bi1;
    const float* bh1;
    const float* Wlin;
    const float* blin;
    float*       out;
    float*       ws;
};

__device__ __forceinline__ unsigned short f2bf(float x) {
    unsigned int u = __builtin_bit_cast(unsigned int, x);
    u += 0x7fffu + ((u >> 16) & 1u);     // RNE
    return (unsigned short)(u >> 16);
}
__device__ __forceinline__ float sigf(float x)  { return 1.0f / (1.0f + __expf(-x)); }
__device__ __forceinline__ float tanh_(float x) { float e = __expf(2.0f * x); return 1.0f - 2.0f / (e + 1.0f); }

template <int K0, int K1>
__device__ __forceinline__ void mfma_regB(const unsigned short* __restrict__ Ab,
                                          const bf16x8* Bf, f32x4* accs) {
#pragma unroll
    for (int kb = K0; kb < K1; ++kb) {
        bf16x8 a = *(const bf16x8*)(Ab + kb * 32);
        accs[kb & 3] = __builtin_amdgcn_mfma_f32_16x16x32_bf16(a, Bf[kb], accs[kb & 3], 0, 0, 0);
    }
}

// FRAGMENT-MAJOR h layout: hbuf[w][kb][lane] with 16 B per lane chunk
// (ushort units: w*16384 + kb*512 + lane*8). Chunk (w,kb,lane=lq*16+lm)
// holds h[w*16+lm][32*kb+8*lq .. +7] — exactly the MFMA B-fragment lane
// (lq*16+lm) of consumer-wave w needs for K-block kb. One load instruction
// = 64 lanes x 16 B CONTIGUOUS 1 KB = 8 fully-used 128 B lines (the old
// row-major layout scattered each instruction over 16 half-used lines).
// Loads are L1/L2-bypass (sc0 sc1): served at the L3 coherence point where
// the agent-atomic publishes landed — no stale cache possible, no fences.
__device__ __forceinline__ void issue_frag_loads_alt(const unsigned short* __restrict__ base,
                                                     int lane, bf16x8* dst) {
    const unsigned short* gp = base + lane * 8;
#pragma unroll
    for (int kb = 0; kb < 32; ++kb)
        asm volatile("global_load_dwordx4 %0, %1, off sc0 sc1"
                     : "=v"(dst[kb]) : "v"(gp + kb * 512));
}
#define VMWAIT(N) do { asm volatile("s_waitcnt vmcnt(" #N ")" ::: "memory"); \
                       __builtin_amdgcn_sched_barrier(0); } while (0)

// ---- FLAT SEQ-VECTOR BARRIER (R4-proven) ----
// seq[bid] (256 dwords, ws bytes [0,1024), poison-based 0xAAAAAAAA+barIdx).
// Each block writes only its own word; wave 0 gather-polls the whole vector
// (64 lanes x dwordx4) and __all-reduces. Producer's s_waitcnt vmcnt(0)
// sits between its h-stores and its seq store => "all seqs >= target" at L3
// implies all h data is at L3; consumer h-loads bypass L1/L2.
__device__ __forceinline__ void gbar_wait_fast(char* wsBase, int tid, unsigned barIdx) {
    if (tid < 64) {
        const u32x4* sp = (const u32x4*)wsBase + tid;   // lane i -> seq[4i..4i+3]
        unsigned tgt = CTR_BASE + barIdx;
        while (true) {
            u32x4 v;
            asm volatile("global_load_dwordx4 %0, %1, off sc0 sc1\n\t"
                         "s_waitcnt vmcnt(0)"
                         : "=v"(v) : "v"(sp) : "memory");
            int ok = (v.x >= tgt) && (v.y >= tgt) && (v.z >= tgt) && (v.w >= tgt);
            if (__all(ok)) break;
            __builtin_amdgcn_s_sleep(1);
        }
    }
    __syncthreads();
}

// arrive: syncthreads -> wave0 publishes this block's 64x 8B h-slices as
// agent-scope atomic stores (write-through to L3) at the FRAGMENT-MAJOR
// offsets (4 contiguous 256 B runs instead of 64 scattered lines) ->
// vmcnt(0) -> own seq word. No fences, no RMW. Waves 1..3 fall through
// immediately into the hidden (reg/LDS) work.
__device__ __forceinline__ void gbar_arrive_fast(char* wsBase, unsigned short* bufBase,
                                                 int pubOff, const unsigned short* sH,
                                                 int bid, int tid, unsigned barIdx) {
    __syncthreads();                      // sH writes visible block-wide
    if (tid < 64) {                       // wave 0 only: 64 rows x 8 B
        unsigned long long v = *(const unsigned long long*)(sH + tid * 4);
        __hip_atomic_store((unsigned long long*)(bufBase + pubOff), v,
                           __ATOMIC_RELAXED, __HIP_MEMORY_SCOPE_AGENT);
    }
    if (tid == 0) {
        asm volatile("s_waitcnt vmcnt(0)" ::: "memory");   // h at L3 before seq
        __hip_atomic_store((unsigned*)(wsBase + (size_t)bid * 4), CTR_BASE + barIdx,
                           __ATOMIC_RELAXED, __HIP_MEMORY_SCOPE_AGENT);
    }
}

// ---- init-only full barrier (fenced; publishes normal cached init stores) ----
__device__ __forceinline__ void gbar_full(char* wsBase, int bid, int tid, unsigned barIdx) {
    __syncthreads();
    if (tid == 0) {
        __builtin_amdgcn_fence(__ATOMIC_RELEASE, "agent");   // flush init stores
        __hip_atomic_store((unsigned*)(wsBase + (size_t)bid * 4), CTR_BASE + barIdx,
                           __ATOMIC_RELAXED, __HIP_MEMORY_SCOPE_AGENT);
    }
    if (tid < 64) {
        const u32x4* sp = (const u32x4*)wsBase + tid;
        unsigned tgt = CTR_BASE + barIdx;
        while (true) {
            u32x4 v;
            asm volatile("global_load_dwordx4 %0, %1, off sc0 sc1\n\t"
                         "s_waitcnt vmcnt(0)"
                         : "=v"(v) : "v"(sp) : "memory");
            int ok = (v.x >= tgt) && (v.y >= tgt) && (v.z >= tgt) && (v.w >= tgt);
            if (__all(ok)) break;
            __builtin_amdgcn_s_sleep(1);
        }
    }
    __syncthreads();
    __builtin_amdgcn_fence(__ATOMIC_ACQUIRE, "agent");       // inv stale L1/L2 copies
}

// 256 blocks x 256 threads, 1 block/CU. Block owns j0=bid*4; gate-rows m=jq*4+gate.
// Wf recurrence (gates0 = Wf*h1(t-1) + Wh0*h0(t-1) + const, Wf = Wi0_y @ Wlin).
// Steady state: NO cache-maintenance ops. h published via write-through agent
// atomics in fragment-major layout; read via fully-coalesced sc0/sc1 bypass
// loads; sync via the flat seq barrier.
__global__ void __launch_bounds__(256, 1) rnn_kernel(Params p) {
    extern __shared__ __align__(16) unsigned short smem[];
    unsigned short* sWf  = smem;
    unsigned short* sWh0 = sWf + SW_MAT;
    unsigned short* sWi1 = sWh0 + SW_MAT;
    unsigned short* sWh1 = sWi1 + SW_MAT;
    float* tmpf = (float*)(smem + 4 * SW_MAT);    // [16][64] Wi0 y-columns fp32
    unsigned short* sH = (unsigned short*)(tmpf + 16 * 64);   // [64][4] h staging

    const int tid = threadIdx.x, bid = blockIdx.x;
    const int lane = tid & 63, w = tid >> 6;
    const int lm = lane & 15, lq = lane >> 4;
    const int bcol0 = w * 16;
    const int bb = bcol0 + lm;
    const int j0 = bid * 4, jj = j0 + lq;
    const int T = p.fcl[0];

    // ws (ushort): seq region [0,8192) (seq[256] dwords in bytes [0,1024),
    // POISON-BASED; rest unused) | h0[2][65536] | h1[2][65536] | wlg[65536],
    // h buffers in FRAGMENT-MAJOR layout [w:4][kb:32][lane:64][8 ushorts].
    unsigned short* x80g = (unsigned short*)p.ws;
    unsigned short* h0g  = x80g + 64 * 128;
    unsigned short* h1g  = h0g + 2 * 65536;
    unsigned short* wlg  = h1g + 2 * 65536;

    // publisher offset (ushorts): wave-sect (tid>>4)*16384, frag (j0>>5)*512,
    // lane chunk (((j0>>3)&3)*16 + (tid&15))*8, intra-chunk j0&7. 8B-aligned.
    const int pubOff = ((tid >> 4) << 14) + ((j0 >> 5) << 9)
                     + ((((j0 >> 3) & 3) * 16 + (tid & 15)) << 3) + (j0 & 7);

    // ---------------- init ----------------
    for (int idx = tid; idx < 16 * 1024; idx += 256) {    // recurrent weights -> LDS bf16
        int m = idx >> 10, k = idx & 1023;
        int gi = m & 3, jq = m >> 2;
        size_t row = (size_t)(gi * HDIM + j0 + jq);
        sWh0[m * WST + k] = f2bf(p.Wh0[row * HDIM + k]);
        sWi1[m * WST + k] = f2bf(p.Wi1[row * HDIM + k]);
        sWh1[m * WST + k] = f2bf(p.Wh1[row * HDIM + k]);
    }
    for (int i = tid; i < 16 * 64; i += 256) {            // Wi0 y-columns -> LDS fp32
        int m = i >> 6, d = i & 63;
        int gi = m & 3, jq = m >> 2;
        tmpf[i] = p.Wi0[(size_t)(gi * HDIM + j0 + jq) * (DDIM + PBDIM) + d];
    }
    __syncthreads();
    {   // Wf = Wi0_y @ Wlin -> LDS bf16. thread: row m=tid>>4, k-chunk c=tid&15.
        int m = tid >> 4, c = tid & 15;
        const float* wrow = tmpf + m * 64;
        for (int pass = 0; pass < 4; ++pass) {
            int k0 = c * 64 + pass * 16;
            float acc[16];
#pragma unroll
            for (int i = 0; i < 16; ++i) acc[i] = 0.f;
            for (int d = 0; d < 64; ++d) {
                float wv = wrow[d];
                const float4* wl = (const float4*)(p.Wlin + (size_t)d * HDIM + k0);
                float4 a0 = wl[0], a1 = wl[1], a2 = wl[2], a3 = wl[3];
                acc[0]  = fmaf(wv, a0.x, acc[0]);  acc[1]  = fmaf(wv, a0.y, acc[1]);
                acc[2]  = fmaf(wv, a0.z, acc[2]);  acc[3]  = fmaf(wv, a0.w, acc[3]);
                acc[4]  = fmaf(wv, a1.x, acc[4]);  acc[5]  = fmaf(wv, a1.y, acc[5]);
                acc[6]  = fmaf(wv, a1.z, acc[6]);  acc[7]  = fmaf(wv, a1.w, acc[7]);
                acc[8]  = fmaf(wv, a2.x, acc[8]);  acc[9]  = fmaf(wv, a2.y, acc[9]);
                acc[10] = fmaf(wv, a2.z, acc[10]); acc[11] = fmaf(wv, a2.w, acc[11]);
                acc[12] = fmaf(wv, a3.x, acc[12]); acc[13] = fmaf(wv, a3.y, acc[13]);
                acc[14] = fmaf(wv, a3.z, acc[14]); acc[15] = fmaf(wv, a3.w, acc[15]);
            }
#pragma unroll
            for (int i = 0; i < 16; ++i) sWf[m * WST + k0 + i] = f2bf(acc[i]);
        }
    }
    // per-lane constants. accT0 = biases + Wi0_pb*pb(b) (t=0 uses y_prev=0!);
    // yb = Wi0_y*blin, added only for t>=1 when y(t-1)=Wlin*h1+blin is live.
    float accT0[4], yb[4], bias1[4];
    {
        int lbl = p.label[bb];
#pragma unroll
        for (int r = 0; r < 4; ++r) {
            float a0_ = p.bi0[r * HDIM + jj] + p.bh0[r * HDIM + jj];
            const float* wpb = p.Wi0 + (size_t)(r * HDIM + jj) * (DDIM + PBDIM) + DDIM;
            const float* mu  = p.mu_pb + lbl * PBDIM;
            for (int q = 0; q < PBDIM; ++q) a0_ = fmaf(wpb[q], mu[q], a0_);
            accT0[r] = a0_;
            float y_ = 0.f;
            const float* wrow = tmpf + (lq * 4 + r) * 64;
            for (int d = 0; d < 64; ++d) y_ = fmaf(wrow[d], p.blin[d], y_);
            yb[r] = y_;
            bias1[r] = p.bi1[r * HDIM + jj] + p.bh1[r * HDIM + jj];
        }
    }
    int gid = bid * 256 + tid;            // 0..65535
    h0g[gid] = 0;                         // zero-init h (any layout of zeros is zeros)
    h1g[gid] = 0;
    // legacy x80 data region is DEAD; bytes [0,1024) stay pristine poison for seq.
    if (bid < 16) {                       // Wlin -> bf16, row-major [64][1024]
        for (int i = 0; i < 16; ++i) {
            int e = bid * 4096 + i * 256 + tid;
            wlg[e] = f2bf(p.Wlin[e]);
        }
    }
    if (bid == 16 && tid < BDIM) {        // aux outputs
        int lbl = p.label[tid];
        float* out_lbl = p.out + (size_t)T * BDIM * DDIM;
        float* out_pb  = out_lbl + BDIM;
        float* out_mu  = out_pb + BDIM * PBDIM;
        float* out_lv  = out_mu + BDIM * PBDIM;
        out_lbl[tid] = (float)lbl;
        for (int q = 0; q < PBDIM; ++q) {
            float mu = p.mu_pb[lbl * PBDIM + q];
            float lv = p.logvar_pb[lbl * PBDIM + q];
            out_pb[tid * PBDIM + q] = mu;
            out_mu[tid * PBDIM + q] = mu;
            out_lv[tid * PBDIM + q] = lv;
        }
    }
    float blin4[4] = {0.f, 0.f, 0.f, 0.f};
    if (bid < 4) {
        int d0 = bid * 16 + lq * 4;
#pragma unroll
        for (int r = 0; r < 4; ++r) blin4[r] = p.blin[d0 + r];
    }
    float c0 = 0.f, c1 = 0.f;
    char* wsBase = (char*)p.ws;

    const f32x4 zf = {0.f, 0.f, 0.f, 0.f};
    unsigned barIdx = 1;
    gbar_full(wsBase, bid, tid, barIdx);  // fenced: publishes all init state to L3

    f32x4 saved0 = zf;                    // Wh0*h0(t-1): zero for t=0 (h0(-1)=0)
    f32x4 saved1 = zf;                    // Wh1*h1(t-1): recomputed each window A
    int cur = 0;
    for (int t = 0; t < T; ++t) {
        // ---- window A: h0(t) = f(Wf*h1(t-1) + saved Wh0-part + const) ----
        {
            gbar_wait_fast(wsBase, tid, barIdx);          // h1(t-1) at L3
            const unsigned short* src = h1g + (size_t)cur * 65536 + (w << 14);
            bf16x8 bfrag[32];
            issue_frag_loads_alt(src, lane, bfrag);
            f32x4 accs[4] = {zf, zf, zf, zf};
            const unsigned short* Ab = sWf + lm * WST + 8 * lq;
            VMWAIT(16);
            mfma_regB<0, 16>(Ab, bfrag, accs);
            VMWAIT(0);
            mfma_regB<16, 32>(Ab, bfrag, accs);
            f32x4 s = accs[0] + accs[1] + accs[2] + accs[3];
            s += saved0;
            float addy = (t > 0) ? 1.f : 0.f;
            float gi_ = s[0] + accT0[0] + addy * yb[0];
            float gf_ = s[1] + accT0[1] + addy * yb[1];
            float gg_ = s[2] + accT0[2] + addy * yb[2];
            float go_ = s[3] + accT0[3] + addy * yb[3];
            c0 = sigf(gf_) * c0 + sigf(gi_) * tanh_(gg_);
            float h = sigf(go_) * tanh_(c0);
            sH[bb * 4 + lq] = f2bf(h);
            gbar_arrive_fast(wsBase, h0g + (size_t)(cur ^ 1) * 65536, pubOff,
                             sH, bid, tid, ++barIdx);
            // ---- hidden in barrier shadow: y(t-1) + Wh1*h1(t-1) from bfrag ----
            if (bid < 4 && t > 0) {                   // y(t-1) = Wlin*h1(t-1) + blin
                f32x4 ya[4] = {zf, zf, zf, zf};
                mfma_regB<0, 32>(wlg + (size_t)(bid * 16 + lm) * 1024 + 8 * lq, bfrag, ya);
                f32x4 sy = ya[0] + ya[1] + ya[2] + ya[3];
                int d0 = bid * 16 + lq * 4;
                float4 y4;
                y4.x = sy[0] + blin4[0]; y4.y = sy[1] + blin4[1];
                y4.z = sy[2] + blin4[2]; y4.w = sy[3] + blin4[3];
                *(float4*)(p.out + (size_t)(t - 1) * BDIM * DDIM + bb * DDIM + d0) = y4;
            }
            {
                f32x4 pa[4] = {zf, zf, zf, zf};
                mfma_regB<0, 32>(sWh1 + lm * WST + 8 * lq, bfrag, pa);
                saved1 = pa[0] + pa[1] + pa[2] + pa[3];
            }
        }
        // ---- window B: h1(t) = f(Wi1*h0(t) + saved Wh1-part + bias) ----
        {
            gbar_wait_fast(wsBase, tid, barIdx);          // h0(t) at L3
            const unsigned short* src = h0g + (size_t)(cur ^ 1) * 65536 + (w << 14);
            bf16x8 bfrag[32];
            issue_frag_loads_alt(src, lane, bfrag);
            f32x4 accs[4] = {zf, zf, zf, zf};
            const unsigned short* Ab = sWi1 + lm * WST + 8 * lq;
            VMWAIT(16);
            mfma_regB<0, 16>(Ab, bfrag, accs);
            VMWAIT(0);
            mfma_regB<16, 32>(Ab, bfrag, accs);
            f32x4 s = accs[0] + accs[1] + accs[2] + accs[3];
            s += saved1;
            float gi_ = s[0] + bias1[0], gf_ = s[1] + bias1[1];
            float gg_ = s[2] + bias1[2], go_ = s[3] + bias1[3];
            c1 = sigf(gf_) * c1 + sigf(gi_) * tanh_(gg_);
            float h = sigf(go_) * tanh_(c1);
            sH[bb * 4 + lq] = f2bf(h);
            gbar_arrive_fast(wsBase, h1g + (size_t)(cur ^ 1) * 65536, pubOff,
                             sH, bid, tid, ++barIdx);
            // ---- hidden in barrier shadow: Wh0*h0(t) for next window A ----
            {
                f32x4 pa[4] = {zf, zf, zf, zf};
                mfma_regB<0, 32>(sWh0 + lm * WST + 8 * lq, bfrag, pa);
                saved0 = pa[0] + pa[1] + pa[2] + pa[3];
            }
        }
        cur ^= 1;
    }
    // ---- tail: y(T-1) (h1(T-1) is in h1g[cur] after the final flip) ----
    gbar_wait_fast(wsBase, tid, barIdx);
    if (bid < 4 && T > 0) {
        bf16x8 bfrag[32];
        issue_frag_loads_alt(h1g + (size_t)cur * 65536 + (w << 14), lane, bfrag);
        VMWAIT(0);
        f32x4 ya[4] = {zf, zf, zf, zf};
        mfma_regB<0, 32>(wlg + (size_t)(bid * 16 + lm) * 1024 + 8 * lq, bfrag, ya);
        f32x4 sy = ya[0] + ya[1] + ya[2] + ya[3];
        int d0 = bid * 16 + lq * 4;
        float4 y4;
        y4.x = sy[0] + blin4[0]; y4.y = sy[1] + blin4[1];
        y4.z = sy[2] + blin4[2]; y4.w = sy[3] + blin4[3];
        *(float4*)(p.out + (size_t)(T - 1) * BDIM * DDIM + bb * DDIM + d0) = y4;
    }
}

extern "C" void kernel_launch(void* const* d_in, const int* in_sizes, int n_in,
                              void* d_out, int out_size, void* d_ws, size_t ws_size,
                              hipStream_t stream) {
    Params p;
    p.label     = (const int*)d_in[0];
    p.fcl       = (const int*)d_in[1];
    p.mu_pb     = (const float*)d_in[2];
    p.logvar_pb = (const float*)d_in[3];
    p.Wi0       = (const float*)d_in[4];
    p.Wh0       = (const float*)d_in[5];
    p.bi0       = (const float*)d_in[6];
    p.bh0       = (const float*)d_in[7];
    p.Wi1       = (const float*)d_in[8];
    p.Wh1       = (const float*)d_in[9];
    p.bi1       = (const float*)d_in[10];
    p.bh1       = (const float*)d_in[11];
    p.Wlin      = (const float*)d_in[12];
    p.blin      = (const float*)d_in[13];
    p.out       = (float*)d_out;
    p.ws        = (float*)d_ws;

    (void)hipFuncSetAttribute((const void*)rnn_kernel,
                              hipFuncAttributeMaxDynamicSharedMemorySize, SMEM_BYTES);
    void* args[] = { &p };
    // Kernel uses only its own ws-based barriers (no cg::grid.sync); coop launch
    // preferred for guaranteed co-residency, fallback to normal launch.
    hipError_t e = hipLaunchCooperativeKernel((void*)rnn_kernel, dim3(256), dim3(256),
                                              args, SMEM_BYTES, stream);
    if (e != hipSuccess) {
        rnn_kernel<<<dim3(256), dim3(256), SMEM_BYTES, stream>>>(p);
    }
}